// Round 4
// baseline (100.665 us; speedup 1.0000x reference)
//
#include <hip/hip_runtime.h>

// NW kernel regression, fused pairwise evaluation.
// queries [N,3] f32, keys [M,3] f32, values [M,8] f32, kernelLen [1] f32
// out [N,8] f32 = (K @ V) / (K @ 1) + 1e-6,
// K[i,j] = max(0, (2+cos(2*pi*d))*(1-d)/3 + sin(2*pi*d)/(2*pi)), d = |q_i-k_j|/L

#define NCH 8          // value channels (fixed per reference)
#define BLK 256        // threads per block = queries per block
#define SPLITS 32      // key splits (grid parallelism)

__device__ __forceinline__ float nw_weight(float qx, float qy, float qz,
                                           float kx, float ky, float kz,
                                           float invL) {
    float dx = qx - kx, dy = qy - ky, dz = qz - kz;
    float d2 = fmaf(dx, dx, fmaf(dy, dy, dz * dz));
    float cd = __builtin_amdgcn_sqrtf(d2) * invL;          // distance in "revolutions"
    float r  = __builtin_amdgcn_fractf(cd);                 // range-reduce for v_sin/v_cos
    float sn = __builtin_amdgcn_sinf(r);                    // sin(2*pi*cd)
    float cs = __builtin_amdgcn_cosf(r);                    // cos(2*pi*cd)
    float t  = (1.0f - cd) * (1.0f / 3.0f);
    // (2+cs)*t + sn/(2pi) = fmaf(cs,t, 2t) + sn*inv2pi
    float w  = fmaf(sn, 0.15915494309189535f, fmaf(cs, t, t + t));
    return fmaxf(w, 0.0f);
}

// Main: block b handles queries [qb*BLK, qb*BLK+BLK), keys [split*KB, +KB).
// Key/value addresses are block-uniform per iteration -> scalar loads.
__global__ __launch_bounds__(BLK) void nw_main(const float* __restrict__ q,
                                               const float* __restrict__ k,
                                               const float* __restrict__ v,
                                               const float* __restrict__ kl,
                                               float* __restrict__ out,
                                               float* __restrict__ den_ws,
                                               int N, int M) {
    const int split = blockIdx.x & (SPLITS - 1);
    const int qb    = blockIdx.x >> 5;   // log2(SPLITS)
    const int i     = qb * BLK + threadIdx.x;
    if (i >= N) return;

    const float qx = q[i * 3 + 0];
    const float qy = q[i * 3 + 1];
    const float qz = q[i * 3 + 2];
    const float invL = 1.0f / kl[0];

    const int KB = M / SPLITS;
    const int j0 = split * KB;

    float num[NCH];
#pragma unroll
    for (int c = 0; c < NCH; ++c) num[c] = 0.0f;
    float den = 0.0f;

#pragma unroll 2
    for (int j = j0; j < j0 + KB; ++j) {
        const float kx = k[j * 3 + 0];
        const float ky = k[j * 3 + 1];
        const float kz = k[j * 3 + 2];
        const float w = nw_weight(qx, qy, qz, kx, ky, kz, invL);
        den += w;
#pragma unroll
        for (int c = 0; c < NCH; ++c)
            num[c] = fmaf(w, v[j * NCH + c], num[c]);
    }

#pragma unroll
    for (int c = 0; c < NCH; ++c)
        atomicAdd(&out[i * NCH + c], num[c]);
    atomicAdd(&den_ws[i], den);
}

// Finalize: out = num/den + 1e-6
__global__ __launch_bounds__(BLK) void nw_finalize(float* __restrict__ out,
                                                   const float* __restrict__ den_ws,
                                                   int total) {
    const int idx = blockIdx.x * BLK + threadIdx.x;
    if (idx >= total) return;
    out[idx] = out[idx] / den_ws[idx >> 3] + 1e-6f;
}

// Fallback (no workspace): one thread per query over all keys. Slow but correct.
__global__ __launch_bounds__(BLK) void nw_full(const float* __restrict__ q,
                                               const float* __restrict__ k,
                                               const float* __restrict__ v,
                                               const float* __restrict__ kl,
                                               float* __restrict__ out,
                                               int N, int M) {
    const int i = blockIdx.x * BLK + threadIdx.x;
    if (i >= N) return;
    const float qx = q[i * 3 + 0];
    const float qy = q[i * 3 + 1];
    const float qz = q[i * 3 + 2];
    const float invL = 1.0f / kl[0];
    float num[NCH];
#pragma unroll
    for (int c = 0; c < NCH; ++c) num[c] = 0.0f;
    float den = 0.0f;
    for (int j = 0; j < M; ++j) {
        const float w = nw_weight(qx, qy, qz, k[j * 3 + 0], k[j * 3 + 1], k[j * 3 + 2], invL);
        den += w;
#pragma unroll
        for (int c = 0; c < NCH; ++c)
            num[c] = fmaf(w, v[j * NCH + c], num[c]);
    }
    const float rden = 1.0f / den;
#pragma unroll
    for (int c = 0; c < NCH; ++c)
        out[i * NCH + c] = num[c] * rden + 1e-6f;
}

extern "C" void kernel_launch(void* const* d_in, const int* in_sizes, int n_in,
                              void* d_out, int out_size, void* d_ws, size_t ws_size,
                              hipStream_t stream) {
    const float* q  = (const float*)d_in[0];
    const float* k  = (const float*)d_in[1];
    const float* v  = (const float*)d_in[2];
    const float* kl = (const float*)d_in[3];
    float* out = (float*)d_out;

    const int N = in_sizes[0] / 3;   // 8192 queries
    const int M = in_sizes[1] / 3;   // 8192 keys

    if (ws_size >= (size_t)N * sizeof(float) && (M % SPLITS) == 0 && (N % BLK) == 0) {
        float* den = (float*)d_ws;
        hipMemsetAsync(out, 0, (size_t)out_size * sizeof(float), stream);
        hipMemsetAsync(den, 0, (size_t)N * sizeof(float), stream);
        dim3 grid((N / BLK) * SPLITS);
        nw_main<<<grid, BLK, 0, stream>>>(q, k, v, kl, out, den, N, M);
        const int total = N * NCH;
        nw_finalize<<<(total + BLK - 1) / BLK, BLK, 0, stream>>>(out, den, total);
    } else {
        nw_full<<<(N + BLK - 1) / BLK, BLK, 0, stream>>>(q, k, v, kl, out, N, M);
    }
}

// Round 5
// 86.912 us; speedup vs baseline: 1.1582x; 1.1582x over previous
//
#include <hip/hip_runtime.h>

// NW kernel regression, fused pairwise evaluation.
// queries [N,3] f32, keys [M,3] f32, values [M,8] f32, kernelLen [1] f32
// out [N,8] f32 = (K @ V) / (K @ 1) + 1e-6,
// K[i,j] = max(0, (2+cos(2*pi*d))*(1-d)/3 + sin(2*pi*d)/(2*pi)), d = |q_i-k_j|/L
//
// Structure: block = 512 thr (8 waves) handles 64 queries x 512 keys.
//   - keys+values staged in LDS (24 KB), inner reads are wave-uniform broadcasts
//   - grid = (N/64) x (M/512) = 128 x 16 = 2048 blocks = 8192 waves (fills all slots)
//   - cross-wave LDS reduce, then deterministic partials in d_ws + reduce kernel
//     (atomic fallback if ws too small)

typedef float v2f __attribute__((ext_vector_type(2)));

#define NCH 8
#define QG 64          // queries per block (= lanes per wave)
#define KSB 512        // keys per superblock (block)
#define TPB 512        // threads per block
#define NWAVE 8        // TPB/64
#define KPW (KSB / NWAVE)  // keys per wave = 64

__device__ __forceinline__ float nw_weight(float qx, float qy, float qz,
                                           float kx, float ky, float kz,
                                           float invL) {
    float dx = qx - kx, dy = qy - ky, dz = qz - kz;
    float d2 = fmaf(dx, dx, fmaf(dy, dy, dz * dz));
    float cd = __builtin_amdgcn_sqrtf(d2) * invL;          // distance in revolutions
    float r  = __builtin_amdgcn_fractf(cd);                 // range-reduce for v_sin/v_cos
    float sn = __builtin_amdgcn_sinf(r);                    // sin(2*pi*cd)
    float cs = __builtin_amdgcn_cosf(r);                    // cos(2*pi*cd)
    float t  = (1.0f - cd) * (1.0f / 3.0f);
    float wt = fmaf(sn, 0.15915494309189535f, fmaf(cs, t, t + t));
    return fmaxf(wt, 0.0f);
}

__global__ __launch_bounds__(TPB) void nw_main(const float* __restrict__ q,
                                               const float* __restrict__ k,
                                               const float* __restrict__ v,
                                               const float* __restrict__ kl,
                                               float* __restrict__ out,
                                               float* __restrict__ part,
                                               float* __restrict__ dws,
                                               int use_partial, int N) {
    // smem: [0, KSB*4)  keys as float4 (xyz+pad)
    //       [KSB*4, KSB*12) values (8 f32/key)
    // overlay after compute: reduce buffer 8*64*10 = 5120 floats (<= 6144)
    __shared__ float smem[KSB * 12];
    float* ks = smem;
    float* vs = smem + KSB * 4;

    const int tid  = threadIdx.x;
    const int lane = tid & 63;
    const int wid  = tid >> 6;
    const int qg   = blockIdx.x;
    const int sb   = blockIdx.y;
    const int j0   = sb * KSB;

    // ---- stage keys+values into LDS (1 key per thread) ----
    {
        const float* kp = k + (size_t)(j0 + tid) * 3;
        const float kx = kp[0], ky = kp[1], kz = kp[2];
        const float4* vp = (const float4*)(v + (size_t)(j0 + tid) * 8);
        const float4 va = vp[0], vb = vp[1];
        ((float4*)ks)[tid]       = make_float4(kx, ky, kz, 0.0f);
        ((float4*)vs)[tid * 2]   = va;
        ((float4*)vs)[tid * 2 + 1] = vb;
    }

    const int i = qg * QG + lane;
    const float qx = q[i * 3 + 0];
    const float qy = q[i * 3 + 1];
    const float qz = q[i * 3 + 2];
    const float invL = 1.0f / kl[0];

    __syncthreads();

    v2f acc[4];
#pragma unroll
    for (int c = 0; c < 4; ++c) acc[c] = v2f{0.0f, 0.0f};
    float den = 0.0f;

    const float4* k4 = (const float4*)ks;
    const float4* v4 = (const float4*)vs;
    const int base = wid * KPW;

#pragma unroll 4
    for (int jj = 0; jj < KPW; ++jj) {
        const int j = base + jj;
        const float4 kk = k4[j];            // wave-uniform ds_read_b128 (broadcast)
        const float4 va = v4[j * 2 + 0];
        const float4 vb = v4[j * 2 + 1];
        const float wt = nw_weight(qx, qy, qz, kk.x, kk.y, kk.z, invL);
        den += wt;
        v2f w2; w2.x = wt; w2.y = wt;
        acc[0] += w2 * v2f{va.x, va.y};
        acc[1] += w2 * v2f{va.z, va.w};
        acc[2] += w2 * v2f{vb.x, vb.y};
        acc[3] += w2 * v2f{vb.z, vb.w};
    }

    __syncthreads();   // everyone done with staged k/v; reuse LDS as reduce buffer
    float* red = smem; // [wid*64+lane][10]
    {
        float vals[10] = {acc[0].x, acc[0].y, acc[1].x, acc[1].y,
                          acc[2].x, acc[2].y, acc[3].x, acc[3].y, den, 0.0f};
        float* r = red + (size_t)(wid * 64 + lane) * 10;
#pragma unroll
        for (int c = 0; c < 10; ++c) r[c] = vals[c];
    }
    __syncthreads();

    // cross-wave sum: thread (c=wid in 0..7, l=lane) handles channel c of query l
    {
        const int c = wid, l = lane;
        float s = 0.0f;
#pragma unroll
        for (int ww = 0; ww < NWAVE; ++ww) s += red[(size_t)(ww * 64 + l) * 10 + c];
        const int gi = qg * QG + l;
        if (use_partial) part[((size_t)sb * 10 + c) * N + gi] = s;
        else             atomicAdd(&out[(size_t)gi * NCH + c], s);

        if (tid < 64) {  // wave 0 also reduces the denominator
            float sd = 0.0f;
#pragma unroll
            for (int ww = 0; ww < NWAVE; ++ww) sd += red[(size_t)(ww * 64 + l) * 10 + 8];
            if (use_partial) part[((size_t)sb * 10 + 8) * N + gi] = sd;
            else             atomicAdd(&dws[gi], sd);
        }
    }
}

// partial path: out[i,c] = (sum_sb num) / (sum_sb den) + 1e-6
__global__ __launch_bounds__(256) void nw_reduce(const float* __restrict__ part,
                                                 float* __restrict__ out,
                                                 int N, int nsb) {
    const int i = blockIdx.x * 256 + threadIdx.x;
    if (i >= N) return;
    float den = 0.0f;
    for (int s = 0; s < nsb; ++s) den += part[((size_t)s * 10 + 8) * N + i];
    const float rd = 1.0f / den;
    float o[NCH];
#pragma unroll
    for (int c = 0; c < NCH; ++c) {
        float s = 0.0f;
        for (int sbi = 0; sbi < nsb; ++sbi) s += part[((size_t)sbi * 10 + c) * N + i];
        o[c] = fmaf(s, rd, 1e-6f);
    }
    float4* o4 = (float4*)(out + (size_t)i * NCH);
    o4[0] = make_float4(o[0], o[1], o[2], o[3]);
    o4[1] = make_float4(o[4], o[5], o[6], o[7]);
}

// atomic path finalize: out = num/den + 1e-6
__global__ __launch_bounds__(256) void nw_finalize(float* __restrict__ out,
                                                   const float* __restrict__ dws,
                                                   int total) {
    const int idx = blockIdx.x * 256 + threadIdx.x;
    if (idx >= total) return;
    out[idx] = out[idx] / dws[idx >> 3] + 1e-6f;
}

// generic fallback: one thread per query over all keys
__global__ __launch_bounds__(256) void nw_full(const float* __restrict__ q,
                                               const float* __restrict__ k,
                                               const float* __restrict__ v,
                                               const float* __restrict__ kl,
                                               float* __restrict__ out,
                                               int N, int M) {
    const int i = blockIdx.x * 256 + threadIdx.x;
    if (i >= N) return;
    const float qx = q[i * 3 + 0], qy = q[i * 3 + 1], qz = q[i * 3 + 2];
    const float invL = 1.0f / kl[0];
    float num[NCH];
#pragma unroll
    for (int c = 0; c < NCH; ++c) num[c] = 0.0f;
    float den = 0.0f;
    for (int j = 0; j < M; ++j) {
        const float wt = nw_weight(qx, qy, qz, k[j * 3 + 0], k[j * 3 + 1], k[j * 3 + 2], invL);
        den += wt;
#pragma unroll
        for (int c = 0; c < NCH; ++c) num[c] = fmaf(wt, v[j * NCH + c], num[c]);
    }
    const float rden = 1.0f / den;
#pragma unroll
    for (int c = 0; c < NCH; ++c) out[i * NCH + c] = fmaf(num[c], rden, 1e-6f);
}

extern "C" void kernel_launch(void* const* d_in, const int* in_sizes, int n_in,
                              void* d_out, int out_size, void* d_ws, size_t ws_size,
                              hipStream_t stream) {
    const float* q  = (const float*)d_in[0];
    const float* k  = (const float*)d_in[1];
    const float* v  = (const float*)d_in[2];
    const float* kl = (const float*)d_in[3];
    float* out = (float*)d_out;

    const int N = in_sizes[0] / 3;   // 8192 queries
    const int M = in_sizes[1] / 3;   // 8192 keys

    if ((N % QG) == 0 && (M % KSB) == 0) {
        const int nsb = M / KSB;
        const size_t need_part = (size_t)nsb * 10 * N * sizeof(float);
        float* part = (float*)d_ws;
        float* dws  = (float*)d_ws;
        int use_partial = (ws_size >= need_part) ? 1 : 0;

        if (!use_partial && ws_size < (size_t)N * sizeof(float)) {
            nw_full<<<(N + 255) / 256, 256, 0, stream>>>(q, k, v, kl, out, N, M);
            return;
        }
        if (!use_partial) {
            hipMemsetAsync(out, 0, (size_t)out_size * sizeof(float), stream);
            hipMemsetAsync(dws, 0, (size_t)N * sizeof(float), stream);
        }
        dim3 grid(N / QG, nsb);
        nw_main<<<grid, TPB, 0, stream>>>(q, k, v, kl, out, part, dws, use_partial, N);
        if (use_partial)
            nw_reduce<<<(N + 255) / 256, 256, 0, stream>>>(part, out, N, nsb);
        else
            nw_finalize<<<(N * NCH + 255) / 256, 256, 0, stream>>>(out, dws, N * NCH);
    } else {
        nw_full<<<(N + 255) / 256, 256, 0, stream>>>(q, k, v, kl, out, N, M);
    }
}

// Round 6
// 58.878 us; speedup vs baseline: 1.7097x; 1.4761x over previous
//
#include <hip/hip_runtime.h>

// NW kernel regression, fused pairwise evaluation with LDS weight LUT.
// queries [N,3] f32, keys [M,3] f32, values [M,8] f32, kernelLen [1] f32
// out [N,8] f32 = (K @ V) / (K @ 1) + 1e-6,
// K[i,j] = max(0, (2+cos(2*pi*d))*(1-d)/3 + sin(2*pi*d)/(2*pi)), d = |q_i-k_j|/L
//
// w as a function of s=(d/L)^2 is smooth (odd powers cancel), w'(s=1)=0 (C1 at
// the clamp boundary), and w=0 for s>=1 -> 1024-cell linear-interp LUT over
// s in [0,1] replaces sqrt/sin/cos (trans-issue dominated round 5 at 82% VALUBusy).

typedef float v2f __attribute__((ext_vector_type(2)));

#define NCH 8
#define QG 64          // queries per block (= lanes per wave)
#define KSB 512        // keys per superblock (block)
#define TPB 512        // threads per block
#define NWAVE 8
#define KPW (KSB / NWAVE)
#define LUTN 1024      // LUT cells over s in [0,1]

__device__ __forceinline__ float nw_weight_exact(float cd) {
    // cd = d/L, exact formula (used only for LUT build + fallback)
    float r  = __builtin_amdgcn_fractf(cd);
    float sn = __builtin_amdgcn_sinf(r);
    float cs = __builtin_amdgcn_cosf(r);
    float t  = (1.0f - cd) * (1.0f / 3.0f);
    float wt = fmaf(sn, 0.15915494309189535f, fmaf(cs, t, t + t));
    return fmaxf(wt, 0.0f);
}

__global__ __launch_bounds__(TPB) void nw_main(const float* __restrict__ q,
                                               const float* __restrict__ k,
                                               const float* __restrict__ v,
                                               const float* __restrict__ kl,
                                               float* __restrict__ part,
                                               int N) {
    __shared__ float2 lut[LUTN + 1];   // (w, w_next - w)
    __shared__ float  smem[KSB * 12];  // keys float4 [0,2048) | values [2048,6144)
    float* ks = smem;
    float* vs = smem + KSB * 4;

    const int tid  = threadIdx.x;
    const int lane = tid & 63;
    const int wid  = tid >> 6;
    const int qg   = blockIdx.x;
    const int sb   = blockIdx.y;
    const int j0   = sb * KSB;

    const float invL = 1.0f / kl[0];

    // ---- build LUT: raw nodes in smem (1025 floats), then (w, dw) pairs ----
    for (int e = tid; e <= LUTN; e += TPB) {
        float s  = (float)e * (1.0f / (float)LUTN);   // s = (d/L)^2 in [0,1]
        float cd = __builtin_amdgcn_sqrtf(s);
        smem[e] = nw_weight_exact(cd);
    }
    __syncthreads();
    for (int e = tid; e <= LUTN; e += TPB) {
        float a = smem[e];
        float b = (e < LUTN) ? smem[e + 1] : a;
        lut[e] = make_float2(a, b - a);
    }
    __syncthreads();

    // ---- stage keys+values into LDS (1 key per thread) ----
    {
        const float* kp = k + (size_t)(j0 + tid) * 3;
        const float kx = kp[0], ky = kp[1], kz = kp[2];
        const float4* vp = (const float4*)(v + (size_t)(j0 + tid) * 8);
        const float4 va = vp[0], vb = vp[1];
        ((float4*)ks)[tid]         = make_float4(kx, ky, kz, 0.0f);
        ((float4*)vs)[tid * 2]     = va;
        ((float4*)vs)[tid * 2 + 1] = vb;
    }

    const int i = qg * QG + lane;
    const float qx = q[i * 3 + 0];
    const float qy = q[i * 3 + 1];
    const float qz = q[i * 3 + 2];
    const float scale = invL * invL * (float)LUTN;

    __syncthreads();

    v2f acc[4];
#pragma unroll
    for (int c = 0; c < 4; ++c) acc[c] = v2f{0.0f, 0.0f};
    float den = 0.0f;

    const float4* k4 = (const float4*)ks;
    const float4* v4 = (const float4*)vs;
    const int base = wid * KPW;

#pragma unroll 4
    for (int jj = 0; jj < KPW; ++jj) {
        const int j = base + jj;
        const float4 kk = k4[j];            // wave-uniform broadcast
        const float4 va = v4[j * 2 + 0];
        const float4 vb = v4[j * 2 + 1];
        float dx = qx - kk.x, dy = qy - kk.y, dz = qz - kk.z;
        float d2 = fmaf(dx, dx, fmaf(dy, dy, dz * dz));
        float fidx = fminf(d2 * scale, (float)LUTN);
        float fl = truncf(fidx);
        float fr = fidx - fl;
        int   idx = (int)fl;
        float2 wd = lut[idx];               // per-lane ds_read_b64
        float wt = fmaf(wd.y, fr, wd.x);
        den += wt;
        v2f w2; w2.x = wt; w2.y = wt;
        acc[0] += w2 * v2f{va.x, va.y};
        acc[1] += w2 * v2f{va.z, va.w};
        acc[2] += w2 * v2f{vb.x, vb.y};
        acc[3] += w2 * v2f{vb.z, vb.w};
    }

    __syncthreads();   // done with staged k/v; reuse as reduce buffer
    float* red = smem; // [wid*64+lane][10]
    {
        float vals[10] = {acc[0].x, acc[0].y, acc[1].x, acc[1].y,
                          acc[2].x, acc[2].y, acc[3].x, acc[3].y, den, 0.0f};
        float* r = red + (size_t)(wid * 64 + lane) * 10;
#pragma unroll
        for (int c = 0; c < 10; ++c) r[c] = vals[c];
    }
    __syncthreads();

    // cross-wave sum: thread (c=wid, l=lane) -> partial[sb][c][qg*64+l]
    {
        const int c = wid, l = lane;
        float s = 0.0f;
#pragma unroll
        for (int ww = 0; ww < NWAVE; ++ww) s += red[(size_t)(ww * 64 + l) * 10 + c];
        const int gi = qg * QG + l;
        part[((size_t)sb * 10 + c) * N + gi] = s;
        if (tid < 64) {
            float sd = 0.0f;
#pragma unroll
            for (int ww = 0; ww < NWAVE; ++ww) sd += red[(size_t)(ww * 64 + l) * 10 + 8];
            part[((size_t)sb * 10 + 8) * N + gi] = sd;
        }
    }
}

// out[i,c] = (sum_sb num) / (sum_sb den) + 1e-6; coalesced row reads
__global__ __launch_bounds__(256) void nw_reduce(const float* __restrict__ part,
                                                 float* __restrict__ out,
                                                 int N, int nsb) {
    const int i = blockIdx.x * 256 + threadIdx.x;
    if (i >= N) return;
    float o[NCH];
#pragma unroll
    for (int c = 0; c < NCH; ++c) o[c] = 0.0f;
    float den = 0.0f;
    for (int sb = 0; sb < nsb; ++sb) {
        const float* base = part + (size_t)sb * 10 * N + i;
        den += base[8 * (size_t)N];
#pragma unroll
        for (int c = 0; c < NCH; ++c) o[c] += base[(size_t)c * N];
    }
    const float rd = 1.0f / den;
    float4* o4 = (float4*)(out + (size_t)i * NCH);
    o4[0] = make_float4(fmaf(o[0], rd, 1e-6f), fmaf(o[1], rd, 1e-6f),
                        fmaf(o[2], rd, 1e-6f), fmaf(o[3], rd, 1e-6f));
    o4[1] = make_float4(fmaf(o[4], rd, 1e-6f), fmaf(o[5], rd, 1e-6f),
                        fmaf(o[6], rd, 1e-6f), fmaf(o[7], rd, 1e-6f));
}

// generic fallback: one thread per query over all keys (exact math)
__global__ __launch_bounds__(256) void nw_full(const float* __restrict__ q,
                                               const float* __restrict__ k,
                                               const float* __restrict__ v,
                                               const float* __restrict__ kl,
                                               float* __restrict__ out,
                                               int N, int M) {
    const int i = blockIdx.x * 256 + threadIdx.x;
    if (i >= N) return;
    const float qx = q[i * 3 + 0], qy = q[i * 3 + 1], qz = q[i * 3 + 2];
    const float invL = 1.0f / kl[0];
    float num[NCH];
#pragma unroll
    for (int c = 0; c < NCH; ++c) num[c] = 0.0f;
    float den = 0.0f;
    for (int j = 0; j < M; ++j) {
        float dx = qx - k[j * 3 + 0], dy = qy - k[j * 3 + 1], dz = qz - k[j * 3 + 2];
        float d2 = fmaf(dx, dx, fmaf(dy, dy, dz * dz));
        float wt = nw_weight_exact(__builtin_amdgcn_sqrtf(d2) * invL);
        den += wt;
#pragma unroll
        for (int c = 0; c < NCH; ++c) num[c] = fmaf(wt, v[j * NCH + c], num[c]);
    }
    const float rden = 1.0f / den;
#pragma unroll
    for (int c = 0; c < NCH; ++c) out[i * NCH + c] = fmaf(num[c], rden, 1e-6f);
}

extern "C" void kernel_launch(void* const* d_in, const int* in_sizes, int n_in,
                              void* d_out, int out_size, void* d_ws, size_t ws_size,
                              hipStream_t stream) {
    const float* q  = (const float*)d_in[0];
    const float* k  = (const float*)d_in[1];
    const float* v  = (const float*)d_in[2];
    const float* kl = (const float*)d_in[3];
    float* out = (float*)d_out;

    const int N = in_sizes[0] / 3;   // 8192 queries
    const int M = in_sizes[1] / 3;   // 8192 keys

    const int nsb = (M + KSB - 1) / KSB;
    const size_t need_part = (size_t)nsb * 10 * N * sizeof(float);

    if ((N % QG) == 0 && (M % KSB) == 0 && ws_size >= need_part) {
        float* part = (float*)d_ws;
        dim3 grid(N / QG, nsb);
        nw_main<<<grid, TPB, 0, stream>>>(q, k, v, kl, part, N);
        nw_reduce<<<(N + 255) / 256, 256, 0, stream>>>(part, out, N, nsb);
    } else {
        nw_full<<<(N + 255) / 256, 256, 0, stream>>>(q, k, v, kl, out, N, M);
    }
}

// Round 7
// 43.952 us; speedup vs baseline: 2.2903x; 1.3396x over previous
//
#include <hip/hip_runtime.h>

// NW kernel regression, fused pairwise evaluation.
// queries [N,3] f32, keys [M,3] f32, values [M,8] f32, kernelLen [1] f32
// out [N,8] f32 = (K @ V) / (K @ 1) + 1e-6,
// K[i,j] = max(0, (2+cos(2*pi*d))*(1-d)/3 + sin(2*pi*d)/(2*pi)), d = |q_i-k_j|/L
//
// Round-7 structure: lane = query, key index is WAVE-UNIFORM and forced into
// an SGPR via readfirstlane -> k/v arrive as s_load (scalar cache broadcast),
// removing the LDS staging that bottlenecked rounds 5/6 (3x ds_read_b128/iter
// saturated the per-CU LDS pipe at ~55us regardless of VALU mix).
// Weight via 1024-cell linear-interp LUT in s=(d/L)^2 domain (C1 at clamp,
// exact-0 beyond) -> no sqrt/sin/cos in the hot loop.

#define NCH 8
#define QG 64          // queries per block (= lanes per wave)
#define KSB 512        // keys per block
#define TPB 512        // threads per block
#define NWAVE 8
#define KPW (KSB / NWAVE)   // keys per wave = 64
#define LUTN 1024

__device__ __forceinline__ float nw_weight_exact(float cd) {
    float r  = __builtin_amdgcn_fractf(cd);
    float sn = __builtin_amdgcn_sinf(r);
    float cs = __builtin_amdgcn_cosf(r);
    float t  = (1.0f - cd) * (1.0f / 3.0f);
    float wt = fmaf(sn, 0.15915494309189535f, fmaf(cs, t, t + t));
    return fmaxf(wt, 0.0f);
}

__global__ __launch_bounds__(TPB) void nw_main(const float* __restrict__ q,
                                               const float* __restrict__ k,
                                               const float* __restrict__ v,
                                               const float* __restrict__ kl,
                                               float* __restrict__ part,
                                               int N) {
    __shared__ float2 lut[LUTN + 1];   // (w, w_next - w)
    __shared__ float  red[TPB * 10];   // LUT-build staging, then reduce buffer

    const int tid  = threadIdx.x;
    const int lane = tid & 63;
    const int wid  = tid >> 6;
    const int qg   = blockIdx.x;
    const int sb   = blockIdx.y;

    const float invL = 1.0f / kl[0];

    // ---- build LUT over s in [0,1] ----
    for (int e = tid; e <= LUTN; e += TPB) {
        float s  = (float)e * (1.0f / (float)LUTN);
        red[e] = nw_weight_exact(__builtin_amdgcn_sqrtf(s));
    }
    __syncthreads();
    for (int e = tid; e <= LUTN; e += TPB) {
        float a = red[e];
        float b = (e < LUTN) ? red[e + 1] : a;
        lut[e] = make_float2(a, b - a);
    }
    __syncthreads();

    const int i = qg * QG + lane;
    const float qx = q[i * 3 + 0];
    const float qy = q[i * 3 + 1];
    const float qz = q[i * 3 + 2];
    const float scale = invL * invL * (float)LUTN;

    // wave-uniform key base, forced into SGPR so k/v loads scalarize
    const int uwid = __builtin_amdgcn_readfirstlane(wid);
    const int jbase = sb * KSB + uwid * KPW;

    float a01 = 0.0f, a23 = 0.0f;  // packed accumulation below
    float acc[NCH];
#pragma unroll
    for (int c = 0; c < NCH; ++c) acc[c] = 0.0f;
    float den = 0.0f;
    (void)a01; (void)a23;

#pragma unroll 4
    for (int jj = 0; jj < KPW; ++jj) {
        const int j = jbase + jj;                 // uniform -> s_load
        const float kx = k[j * 3 + 0];
        const float ky = k[j * 3 + 1];
        const float kz = k[j * 3 + 2];
        const float4 va = *(const float4*)(v + (size_t)j * 8);
        const float4 vb = *(const float4*)(v + (size_t)j * 8 + 4);

        float dx = qx - kx, dy = qy - ky, dz = qz - kz;
        float d2 = fmaf(dx, dx, fmaf(dy, dy, dz * dz));
        float fidx = fminf(d2 * scale, (float)LUTN);
        float fl = truncf(fidx);
        float fr = fidx - fl;
        float2 wd = lut[(int)fl];                 // only LDS op in the loop
        float wt = fmaf(wd.y, fr, wd.x);

        den += wt;
        acc[0] = fmaf(wt, va.x, acc[0]);
        acc[1] = fmaf(wt, va.y, acc[1]);
        acc[2] = fmaf(wt, va.z, acc[2]);
        acc[3] = fmaf(wt, va.w, acc[3]);
        acc[4] = fmaf(wt, vb.x, acc[4]);
        acc[5] = fmaf(wt, vb.y, acc[5]);
        acc[6] = fmaf(wt, vb.z, acc[6]);
        acc[7] = fmaf(wt, vb.w, acc[7]);
    }

    __syncthreads();   // LUT-phase done; red[] free for reduction
    {
        float* r = red + (size_t)(wid * 64 + lane) * 10;
#pragma unroll
        for (int c = 0; c < NCH; ++c) r[c] = acc[c];
        r[8] = den;
        r[9] = 0.0f;
    }
    __syncthreads();

    // cross-wave sum: thread (c=wid, l=lane) -> part[sb][c][qg*64+l]
    {
        const int c = wid, l = lane;
        float s = 0.0f;
#pragma unroll
        for (int ww = 0; ww < NWAVE; ++ww) s += red[(size_t)(ww * 64 + l) * 10 + c];
        const int gi = qg * QG + l;
        part[((size_t)sb * 10 + c) * N + gi] = s;
        if (tid < 64) {
            float sd = 0.0f;
#pragma unroll
            for (int ww = 0; ww < NWAVE; ++ww) sd += red[(size_t)(ww * 64 + l) * 10 + 8];
            part[((size_t)sb * 10 + 8) * N + gi] = sd;
        }
    }
}

// out[i,c] = (sum_sb num) / (sum_sb den) + 1e-6; coalesced row reads
__global__ __launch_bounds__(256) void nw_reduce(const float* __restrict__ part,
                                                 float* __restrict__ out,
                                                 int N, int nsb) {
    const int i = blockIdx.x * 256 + threadIdx.x;
    if (i >= N) return;
    float o[NCH];
#pragma unroll
    for (int c = 0; c < NCH; ++c) o[c] = 0.0f;
    float den = 0.0f;
    for (int sb = 0; sb < nsb; ++sb) {
        const float* base = part + (size_t)sb * 10 * N + i;
        den += base[8 * (size_t)N];
#pragma unroll
        for (int c = 0; c < NCH; ++c) o[c] += base[(size_t)c * N];
    }
    const float rd = 1.0f / den;
    float4* o4 = (float4*)(out + (size_t)i * NCH);
    o4[0] = make_float4(fmaf(o[0], rd, 1e-6f), fmaf(o[1], rd, 1e-6f),
                        fmaf(o[2], rd, 1e-6f), fmaf(o[3], rd, 1e-6f));
    o4[1] = make_float4(fmaf(o[4], rd, 1e-6f), fmaf(o[5], rd, 1e-6f),
                        fmaf(o[6], rd, 1e-6f), fmaf(o[7], rd, 1e-6f));
}

// generic fallback: one thread per query over all keys (exact math)
__global__ __launch_bounds__(256) void nw_full(const float* __restrict__ q,
                                               const float* __restrict__ k,
                                               const float* __restrict__ v,
                                               const float* __restrict__ kl,
                                               float* __restrict__ out,
                                               int N, int M) {
    const int i = blockIdx.x * 256 + threadIdx.x;
    if (i >= N) return;
    const float qx = q[i * 3 + 0], qy = q[i * 3 + 1], qz = q[i * 3 + 2];
    const float invL = 1.0f / kl[0];
    float num[NCH];
#pragma unroll
    for (int c = 0; c < NCH; ++c) num[c] = 0.0f;
    float den = 0.0f;
    for (int j = 0; j < M; ++j) {
        float dx = qx - k[j * 3 + 0], dy = qy - k[j * 3 + 1], dz = qz - k[j * 3 + 2];
        float d2 = fmaf(dx, dx, fmaf(dy, dy, dz * dz));
        float wt = nw_weight_exact(__builtin_amdgcn_sqrtf(d2) * invL);
        den += wt;
#pragma unroll
        for (int c = 0; c < NCH; ++c) num[c] = fmaf(wt, v[j * NCH + c], num[c]);
    }
    const float rden = 1.0f / den;
#pragma unroll
    for (int c = 0; c < NCH; ++c) out[i * NCH + c] = fmaf(num[c], rden, 1e-6f);
}

extern "C" void kernel_launch(void* const* d_in, const int* in_sizes, int n_in,
                              void* d_out, int out_size, void* d_ws, size_t ws_size,
                              hipStream_t stream) {
    const float* q  = (const float*)d_in[0];
    const float* k  = (const float*)d_in[1];
    const float* v  = (const float*)d_in[2];
    const float* kl = (const float*)d_in[3];
    float* out = (float*)d_out;

    const int N = in_sizes[0] / 3;   // 8192 queries
    const int M = in_sizes[1] / 3;   // 8192 keys

    const int nsb = (M + KSB - 1) / KSB;
    const size_t need_part = (size_t)nsb * 10 * N * sizeof(float);

    if ((N % QG) == 0 && (M % KSB) == 0 && ws_size >= need_part) {
        float* part = (float*)d_ws;
        dim3 grid(N / QG, nsb);
        nw_main<<<grid, TPB, 0, stream>>>(q, k, v, kl, part, N);
        nw_reduce<<<(N + 255) / 256, 256, 0, stream>>>(part, out, N, nsb);
    } else {
        nw_full<<<(N + 255) / 256, 256, 0, stream>>>(q, k, v, kl, out, N, M);
    }
}

// Round 9
// 43.335 us; speedup vs baseline: 2.3229x; 1.0142x over previous
//
#include <hip/hip_runtime.h>

// NW kernel regression, fused pairwise evaluation.
// queries [N,3] f32, keys [M,3] f32, values [M,8] f32, kernelLen [1] f32
// out [N,8] f32 = (K @ V) / (K @ 1) + 1e-6,
// K[i,j] = max(0, (2+cos(2*pi*d))*(1-d)/3 + sin(2*pi*d)/(2*pi)), d = |q_i-k_j|/L
//
// Round-8 structure (lane = query, wave-uniform keys via readfirstlane -> s_load):
//  - weight via NEAREST-NEIGHBOR 4096-cell LUT in s=(d/L)^2 domain, b32 read
//    (round 7's b64 interp LUT cost 7 VALU + 2-bank gather; w is C4-flat at the
//    s=1 clamp so nearest @4096 adds only ~1e-4 output error)
//  - packed v2f accumulation -> v_pk_fma_f32 for the 8 channel FMAs
//  - deterministic partials in d_ws + reduce kernel

typedef float v2f __attribute__((ext_vector_type(2)));

#define NCH 8
#define QG 64          // queries per block (= lanes per wave)
#define KSB 512        // keys per block
#define TPB 512        // threads per block
#define NWAVE 8
#define KPW (KSB / NWAVE)   // keys per wave = 64
#define LUTN 4096

__device__ __forceinline__ float nw_weight_exact(float cd) {
    float r  = __builtin_amdgcn_fractf(cd);
    float sn = __builtin_amdgcn_sinf(r);
    float cs = __builtin_amdgcn_cosf(r);
    float t  = (1.0f - cd) * (1.0f / 3.0f);
    float wt = fmaf(sn, 0.15915494309189535f, fmaf(cs, t, t + t));
    return fmaxf(wt, 0.0f);
}

__global__ __launch_bounds__(TPB) void nw_main(const float* __restrict__ q,
                                               const float* __restrict__ k,
                                               const float* __restrict__ v,
                                               const float* __restrict__ kl,
                                               float* __restrict__ part,
                                               int N) {
    __shared__ float lutw[LUTN + 1];   // w at s = e/LUTN
    __shared__ float red[TPB * 10];    // cross-wave reduce buffer

    const int tid  = threadIdx.x;
    const int lane = tid & 63;
    const int wid  = tid >> 6;
    const int qg   = blockIdx.x;
    const int sb   = blockIdx.y;

    const float invL = 1.0f / kl[0];

    // ---- build LUT over s in [0,1] (4097 exact evals, amortized) ----
    for (int e = tid; e <= LUTN; e += TPB) {
        float s = (float)e * (1.0f / (float)LUTN);
        lutw[e] = nw_weight_exact(__builtin_amdgcn_sqrtf(s));
    }
    __syncthreads();

    const int i = qg * QG + lane;
    const float qx = q[i * 3 + 0];
    const float qy = q[i * 3 + 1];
    const float qz = q[i * 3 + 2];
    const float scale = invL * invL * (float)LUTN;

    // wave-uniform key base in SGPR -> k/v scalarize to s_load
    const int uwid = __builtin_amdgcn_readfirstlane(wid);
    const int jbase = sb * KSB + uwid * KPW;

    v2f acc4[4];
#pragma unroll
    for (int c = 0; c < 4; ++c) acc4[c] = v2f{0.0f, 0.0f};
    float den = 0.0f;

#pragma unroll 4
    for (int jj = 0; jj < KPW; ++jj) {
        const int j = jbase + jj;                 // uniform -> s_load
        const float kx = k[j * 3 + 0];
        const float ky = k[j * 3 + 1];
        const float kz = k[j * 3 + 2];
        const v2f* vv = (const v2f*)(v + (size_t)j * 8);
        const v2f v0 = vv[0], v1 = vv[1], v2 = vv[2], v3 = vv[3];

        float dx = qx - kx, dy = qy - ky, dz = qz - kz;
        float d2 = fmaf(dx, dx, fmaf(dy, dy, dz * dz));
        float fidx = fminf(fmaf(d2, scale, 0.5f), (float)LUTN);  // round + clamp
        int   idx  = (int)fidx;
        float wt   = lutw[idx];                   // single b32 gather

        den += wt;
        v2f w2; w2.x = wt; w2.y = wt;
        acc4[0] += w2 * v0;                       // v_pk_fma_f32
        acc4[1] += w2 * v1;
        acc4[2] += w2 * v2;
        acc4[3] += w2 * v3;
    }

    __syncthreads();   // LUT phase over; red[] free
    {
        float vals[10] = {acc4[0].x, acc4[0].y, acc4[1].x, acc4[1].y,
                          acc4[2].x, acc4[2].y, acc4[3].x, acc4[3].y, den, 0.0f};
        float* r = red + (size_t)(wid * 64 + lane) * 10;
#pragma unroll
        for (int c = 0; c < 10; ++c) r[c] = vals[c];
    }
    __syncthreads();

    // cross-wave sum: thread (c=wid, l=lane) -> part[sb][c][qg*64+l]
    {
        const int c = wid, l = lane;
        float s = 0.0f;
#pragma unroll
        for (int ww = 0; ww < NWAVE; ++ww) s += red[(size_t)(ww * 64 + l) * 10 + c];
        const int gi = qg * QG + l;
        part[((size_t)sb * 10 + c) * N + gi] = s;
        if (tid < 64) {
            float sd = 0.0f;
#pragma unroll
            for (int ww = 0; ww < NWAVE; ++ww) sd += red[(size_t)(ww * 64 + l) * 10 + 8];
            part[((size_t)sb * 10 + 8) * N + gi] = sd;
        }
    }
}

// out[i,c] = (sum_sb num) / (sum_sb den) + 1e-6; coalesced row reads
__global__ __launch_bounds__(256) void nw_reduce(const float* __restrict__ part,
                                                 float* __restrict__ out,
                                                 int N, int nsb) {
    const int i = blockIdx.x * 256 + threadIdx.x;
    if (i >= N) return;
    float o[NCH];
#pragma unroll
    for (int c = 0; c < NCH; ++c) o[c] = 0.0f;
    float den = 0.0f;
    for (int sb = 0; sb < nsb; ++sb) {
        const float* base = part + (size_t)sb * 10 * N + i;
        den += base[8 * (size_t)N];
#pragma unroll
        for (int c = 0; c < NCH; ++c) o[c] += base[(size_t)c * N];
    }
    const float rd = 1.0f / den;
    float4* o4 = (float4*)(out + (size_t)i * NCH);
    o4[0] = make_float4(fmaf(o[0], rd, 1e-6f), fmaf(o[1], rd, 1e-6f),
                        fmaf(o[2], rd, 1e-6f), fmaf(o[3], rd, 1e-6f));
    o4[1] = make_float4(fmaf(o[4], rd, 1e-6f), fmaf(o[5], rd, 1e-6f),
                        fmaf(o[6], rd, 1e-6f), fmaf(o[7], rd, 1e-6f));
}

// generic fallback: one thread per query over all keys (exact math)
__global__ __launch_bounds__(256) void nw_full(const float* __restrict__ q,
                                               const float* __restrict__ k,
                                               const float* __restrict__ v,
                                               const float* __restrict__ kl,
                                               float* __restrict__ out,
                                               int N, int M) {
    const int i = blockIdx.x * 256 + threadIdx.x;
    if (i >= N) return;
    const float qx = q[i * 3 + 0], qy = q[i * 3 + 1], qz = q[i * 3 + 2];
    const float invL = 1.0f / kl[0];
    float num[NCH];
#pragma unroll
    for (int c = 0; c < NCH; ++c) num[c] = 0.0f;
    float den = 0.0f;
    for (int j = 0; j < M; ++j) {
        float dx = qx - k[j * 3 + 0], dy = qy - k[j * 3 + 1], dz = qz - k[j * 3 + 2];
        float d2 = fmaf(dx, dx, fmaf(dy, dy, dz * dz));
        float wt = nw_weight_exact(__builtin_amdgcn_sqrtf(d2) * invL);
        den += wt;
#pragma unroll
        for (int c = 0; c < NCH; ++c) num[c] = fmaf(wt, v[j * NCH + c], num[c]);
    }
    const float rden = 1.0f / den;
#pragma unroll
    for (int c = 0; c < NCH; ++c) out[i * NCH + c] = fmaf(num[c], rden, 1e-6f);
}

extern "C" void kernel_launch(void* const* d_in, const int* in_sizes, int n_in,
                              void* d_out, int out_size, void* d_ws, size_t ws_size,
                              hipStream_t stream) {
    const float* q  = (const float*)d_in[0];
    const float* k  = (const float*)d_in[1];
    const float* v  = (const float*)d_in[2];
    const float* kl = (const float*)d_in[3];
    float* out = (float*)d_out;

    const int N = in_sizes[0] / 3;   // 8192 queries
    const int M = in_sizes[1] / 3;   // 8192 keys

    const int nsb = (M + KSB - 1) / KSB;
    const size_t need_part = (size_t)nsb * 10 * N * sizeof(float);

    if ((N % QG) == 0 && (M % KSB) == 0 && ws_size >= need_part) {
        float* part = (float*)d_ws;
        dim3 grid(N / QG, nsb);
        nw_main<<<grid, TPB, 0, stream>>>(q, k, v, kl, part, N);
        nw_reduce<<<(N + 255) / 256, 256, 0, stream>>>(part, out, N, nsb);
    } else {
        nw_full<<<(N + 255) / 256, 256, 0, stream>>>(q, k, v, kl, out, N, M);
    }
}